// Round 1
// baseline (646.807 us; speedup 1.0000x reference)
//
#include <hip/hip_runtime.h>
#include <math.h>

// CMCV3Loss: B=512, S=8, D=128, H=64. Inputs: mod1_v1, mod1_v2, mod2_v1, mod2_v2 (4096x128 fp32), seq_len.
// ws layout (floats): invsh[4*4096] | invpv[4*4096] | invfull[4*4096] | accum slots (16 x stride 32)
#define INV_T 14.285714285714286f
#define ACC_OFF 49152
#define EPS_N 1e-8f

__device__ __forceinline__ const float* pick4(const float* a, const float* b,
                                              const float* c, const float* d, int i) {
    return i == 0 ? a : i == 1 ? b : i == 2 ? c : d;
}

__global__ void k_zero(float* __restrict__ ws) {
    ws[ACC_OFF + threadIdx.x] = 0.0f;  // 512 threads, zero all accum slots
}

__global__ __launch_bounds__(256) void k_norm(const float* __restrict__ in0, const float* __restrict__ in1,
                                              const float* __restrict__ in2, const float* __restrict__ in3,
                                              float* __restrict__ ws) {
    int gtid = blockIdx.x * 256 + threadIdx.x;
    int wid = gtid >> 6;            // one wave per row
    int lane = threadIdx.x & 63;
    int inputIdx = wid >> 12;       // 4096 rows per input
    int row = wid & 4095;
    const float* src = pick4(in0, in1, in2, in3, inputIdx);
    float2 v = *(const float2*)(src + (size_t)row * 128 + lane * 2);  // lanes 0..31 = sh half, 32..63 = pv half
    float s = v.x * v.x + v.y * v.y;
    #pragma unroll
    for (int off = 16; off; off >>= 1) s += __shfl_xor(s, off, 32);
    float other = __shfl_xor(s, 32, 64);
    float sh2 = (lane < 32) ? s : other;
    float pv2 = (lane < 32) ? other : s;
    if (lane == 0) {
        ws[             inputIdx * 4096 + row] = 1.0f / fmaxf(sqrtf(sh2), EPS_N);
        ws[4 * 4096  +  inputIdx * 4096 + row] = 1.0f / fmaxf(sqrtf(pv2), EPS_N);
        ws[8 * 4096  +  inputIdx * 4096 + row] = 1.0f / fmaxf(sqrtf(sh2 + pv2), EPS_N);
    }
}

// ---------- temporal: per input, loss_i = lse_{j!=i}(dot(nf_i,nf_j)/T) - sim[i, pos0] ----------
// grid (128, 4): 32-row tiles x 4 inputs. block 256 = 64 cols x 4 row-groups of 8.
__global__ __launch_bounds__(256) void k_temporal(const float* __restrict__ in0, const float* __restrict__ in1,
                                                  const float* __restrict__ in2, const float* __restrict__ in3,
                                                  float* __restrict__ ws) {
    __shared__ __align__(16) float rowbuf[32 * 128];   // broadcast-read: no pad needed
    __shared__ __align__(16) float colbuf[64 * 132];   // +4 pad: lane-varying b128 at bank floor
    const int tid = threadIdx.x;
    const int inputIdx = blockIdx.y;
    const int rowbase = blockIdx.x * 32;
    const float* src = pick4(in0, in1, in2, in3, inputIdx);
    const float* ivf = ws + 8 * 4096 + inputIdx * 4096;

    #pragma unroll
    for (int i = 0; i < 4; i++) {                       // stage 32x128 rows, normalized
        int e = tid + i * 256;
        int vr = e >> 5, k4 = e & 31;
        float4 f = *(const float4*)(src + (size_t)(rowbase + vr) * 128 + k4 * 4);
        float sc = ivf[rowbase + vr];
        float4 o; o.x = f.x * sc; o.y = f.y * sc; o.z = f.z * sc; o.w = f.w * sc;
        *(float4*)(rowbuf + vr * 128 + k4 * 4) = o;
    }
    __syncthreads();

    const int c = tid & 63, g = tid >> 6;
    float sm[8], pvv[8];
    #pragma unroll
    for (int r = 0; r < 8; r++) { sm[r] = 0.0f; pvv[r] = 0.0f; }

    for (int t = 0; t < 64; t++) {
        int colbase = t * 64;
        #pragma unroll
        for (int i = 0; i < 8; i++) {                   // stage 64x128 cols, normalized
            int e = tid + i * 256;
            int vr = e >> 5, k4 = e & 31;
            float4 f = *(const float4*)(src + (size_t)(colbase + vr) * 128 + k4 * 4);
            float sc = ivf[colbase + vr];
            float4 o; o.x = f.x * sc; o.y = f.y * sc; o.z = f.z * sc; o.w = f.w * sc;
            *(float4*)(colbuf + vr * 132 + k4 * 4) = o;
        }
        __syncthreads();

        float acc[8];
        #pragma unroll
        for (int r = 0; r < 8; r++) acc[r] = 0.0f;
        for (int k4 = 0; k4 < 32; k4++) {
            float4 cv = *(const float4*)(colbuf + c * 132 + k4 * 4);
            #pragma unroll
            for (int r = 0; r < 8; r++) {
                float4 rv = *(const float4*)(rowbuf + (g * 8 + r) * 128 + k4 * 4);
                acc[r] = fmaf(rv.x, cv.x, fmaf(rv.y, cv.y, fmaf(rv.z, cv.z, fmaf(rv.w, cv.w, acc[r]))));
            }
        }
        int colglob = colbase + c;
        #pragma unroll
        for (int r = 0; r < 8; r++) {
            int rowglob = rowbase + g * 8 + r;
            float v = acc[r] * INV_T;
            float ex = __expf(v - INV_T);               // fixed max-shift: sim <= 1/T always
            sm[r] += (colglob != rowglob) ? ex : 0.0f;
            int poscol = (rowglob & ~7) | (((rowglob & 7) == 0) ? 1 : 0);
            if (colglob == poscol) pvv[r] = v;
        }
        __syncthreads();
    }

    float blocksum = 0.0f;
    #pragma unroll
    for (int r = 0; r < 8; r++) {
        float s = sm[r], p = pvv[r];
        #pragma unroll
        for (int off = 32; off; off >>= 1) { s += __shfl_xor(s, off); p += __shfl_xor(p, off); }
        blocksum += __logf(s) + INV_T - p;
    }
    if (c == 0) atomicAdd(ws + ACC_OFF + 32 * (8 + (blockIdx.x & 7)), blocksum);
}

// ---------- contrastive: per (call, p), 1024x1024 gram of 64-d halves ----------
// z[n] = (n<512 ? A : B) row (n&511)*8+p, cols off..off+63. loss = lse_{m!=n} - sim[n, n^512]
// grid (16, 8, 4): 64-row tiles x p x call. block 256 = 64 cols x 4 row-groups of 16.
__global__ __launch_bounds__(256) void k_contrastive(const float* __restrict__ in0, const float* __restrict__ in1,
                                                     const float* __restrict__ in2, const float* __restrict__ in3,
                                                     float* __restrict__ ws) {
    __shared__ __align__(16) float rowbuf[64 * 64];
    __shared__ __align__(16) float colbuf[64 * 68];
    const int tid = threadIdx.x;
    const int call = blockIdx.z;
    const int tp = blockIdx.y;
    const int rowbase = blockIdx.x * 64;

    int aIdx, bIdx, off;
    if (call == 0)      { aIdx = 0; bIdx = 2; off = 0; }   // shared view1: sh(mod1_v1), sh(mod2_v1)
    else if (call == 1) { aIdx = 1; bIdx = 3; off = 0; }   // shared view2
    else if (call == 2) { aIdx = 0; bIdx = 1; off = 64; }  // private mod1: pv(v1), pv(v2)
    else                { aIdx = 2; bIdx = 3; off = 64; }  // private mod2
    const float* A  = pick4(in0, in1, in2, in3, aIdx);
    const float* Bp = pick4(in0, in1, in2, in3, bIdx);
    const float* ivbase = ws + (off ? 4 * 4096 : 0);
    const float* ivA = ivbase + aIdx * 4096;
    const float* ivB = ivbase + bIdx * 4096;

    {   // stage rows (tile is entirely within one source since 64 | 512)
        const float* sp  = (rowbase < 512) ? A : Bp;
        const float* ivp = (rowbase < 512) ? ivA : ivB;
        const int nb = rowbase & 511;
        #pragma unroll
        for (int i = 0; i < 4; i++) {
            int e = tid + i * 256;
            int vr = e >> 4, k4 = e & 15;
            int fr = (nb + vr) * 8 + tp;
            float4 f = *(const float4*)(sp + (size_t)fr * 128 + off + k4 * 4);
            float sc = ivp[fr];
            float4 o; o.x = f.x * sc; o.y = f.y * sc; o.z = f.z * sc; o.w = f.w * sc;
            *(float4*)(rowbuf + vr * 64 + k4 * 4) = o;
        }
    }
    __syncthreads();

    const int c = tid & 63, g = tid >> 6;
    float sm[16], pvv[16];
    #pragma unroll
    for (int r = 0; r < 16; r++) { sm[r] = 0.0f; pvv[r] = 0.0f; }

    for (int t = 0; t < 16; t++) {
        int colbase = t * 64;
        const float* csp = (colbase < 512) ? A : Bp;
        const float* civ = (colbase < 512) ? ivA : ivB;
        int cb = colbase & 511;
        #pragma unroll
        for (int i = 0; i < 4; i++) {
            int e = tid + i * 256;
            int vr = e >> 4, k4 = e & 15;
            int fr = (cb + vr) * 8 + tp;
            float4 f = *(const float4*)(csp + (size_t)fr * 128 + off + k4 * 4);
            float sc = civ[fr];
            float4 o; o.x = f.x * sc; o.y = f.y * sc; o.z = f.z * sc; o.w = f.w * sc;
            *(float4*)(colbuf + vr * 68 + k4 * 4) = o;
        }
        __syncthreads();

        float acc[16];
        #pragma unroll
        for (int r = 0; r < 16; r++) acc[r] = 0.0f;
        for (int k4 = 0; k4 < 16; k4++) {
            float4 cv = *(const float4*)(colbuf + c * 68 + k4 * 4);
            #pragma unroll
            for (int r = 0; r < 16; r++) {
                float4 rv = *(const float4*)(rowbuf + (g * 16 + r) * 64 + k4 * 4);
                acc[r] = fmaf(rv.x, cv.x, fmaf(rv.y, cv.y, fmaf(rv.z, cv.z, fmaf(rv.w, cv.w, acc[r]))));
            }
        }
        int colglob = colbase + c;
        #pragma unroll
        for (int r = 0; r < 16; r++) {
            int rowglob = rowbase + g * 16 + r;
            float v = acc[r] * INV_T;
            float ex = __expf(v - INV_T);
            sm[r] += (colglob != rowglob) ? ex : 0.0f;
            if (colglob == (rowglob ^ 512)) pvv[r] = v;
        }
        __syncthreads();
    }

    float blocksum = 0.0f;
    #pragma unroll
    for (int r = 0; r < 16; r++) {
        float s = sm[r], p = pvv[r];
        #pragma unroll
        for (int off2 = 32; off2; off2 >>= 1) { s += __shfl_xor(s, off2); p += __shfl_xor(p, off2); }
        blocksum += __logf(s) + INV_T - p;
    }
    if (c == 0) atomicAdd(ws + ACC_OFF + 32 * ((blockIdx.x + 2 * blockIdx.y) & 7), blocksum);
}

// ---------- ortho: mean(relu(dot of normalized halves)), 6 terms x 4096 rows ----------
__global__ __launch_bounds__(256) void k_ortho(const float* __restrict__ in0, const float* __restrict__ in1,
                                               const float* __restrict__ in2, const float* __restrict__ in3,
                                               float* __restrict__ ws) {
    const int term = blockIdx.y;
    const int row = blockIdx.x * 256 + threadIdx.x;
    int aIdx, aOff, bIdx, bOff;
    switch (term) {
        case 0:  aIdx = 0; aOff = 0;  bIdx = 0; bOff = 64; break;  // sh(f1[0]) vs pv(f1[0])
        case 1:  aIdx = 2; aOff = 0;  bIdx = 2; bOff = 64; break;  // f1[1] = in2
        case 2:  aIdx = 1; aOff = 0;  bIdx = 1; bOff = 64; break;  // f2[0] = in1
        case 3:  aIdx = 3; aOff = 0;  bIdx = 3; bOff = 64; break;  // f2[1] = in3
        case 4:  aIdx = 0; aOff = 64; bIdx = 2; bOff = 64; break;  // pv(f1[0]) vs pv(f1[1])
        default: aIdx = 1; aOff = 64; bIdx = 3; bOff = 64; break;  // pv(f2[0]) vs pv(f2[1])
    }
    const float* A  = pick4(in0, in1, in2, in3, aIdx) + (size_t)row * 128 + aOff;
    const float* Bv = pick4(in0, in1, in2, in3, bIdx) + (size_t)row * 128 + bOff;
    float ia = ws[(aOff ? 4 * 4096 : 0) + aIdx * 4096 + row];
    float ib = ws[(bOff ? 4 * 4096 : 0) + bIdx * 4096 + row];
    float d = 0.0f;
    #pragma unroll
    for (int k = 0; k < 16; k++) {
        float4 x = *(const float4*)(A + k * 4);
        float4 y = *(const float4*)(Bv + k * 4);
        d = fmaf(x.x, y.x, fmaf(x.y, y.y, fmaf(x.z, y.z, fmaf(x.w, y.w, d))));
    }
    float val = fmaxf(d * ia * ib, 0.0f);
    #pragma unroll
    for (int off = 32; off; off >>= 1) val += __shfl_xor(val, off);
    if ((threadIdx.x & 63) == 0)
        atomicAdd(ws + ACC_OFF + 32 * (8 + ((blockIdx.x + blockIdx.y) & 7)), val);
}

__global__ void k_final(const float* __restrict__ ws, float* __restrict__ out) {
    if (threadIdx.x == 0) {
        float csum = 0.0f, tsum = 0.0f;
        for (int i = 0; i < 8; i++)  csum += ws[ACC_OFF + 32 * i];
        for (int i = 8; i < 16; i++) tsum += ws[ACC_OFF + 32 * i];
        out[0] = csum * (1.0f / 8192.0f) + tsum * (1.0f / 4096.0f);
    }
}

extern "C" void kernel_launch(void* const* d_in, const int* in_sizes, int n_in,
                              void* d_out, int out_size, void* d_ws, size_t ws_size,
                              hipStream_t stream) {
    (void)in_sizes; (void)n_in; (void)out_size; (void)ws_size;
    const float* in0 = (const float*)d_in[0];  // mod1_v1
    const float* in1 = (const float*)d_in[1];  // mod1_v2
    const float* in2 = (const float*)d_in[2];  // mod2_v1
    const float* in3 = (const float*)d_in[3];  // mod2_v2
    float* ws = (float*)d_ws;
    float* out = (float*)d_out;

    hipLaunchKernelGGL(k_zero, dim3(1), dim3(512), 0, stream, ws);
    hipLaunchKernelGGL(k_norm, dim3(4096), dim3(256), 0, stream, in0, in1, in2, in3, ws);
    hipLaunchKernelGGL(k_contrastive, dim3(16, 8, 4), dim3(256), 0, stream, in0, in1, in2, in3, ws);
    hipLaunchKernelGGL(k_temporal, dim3(128, 4), dim3(256), 0, stream, in0, in1, in2, in3, ws);
    hipLaunchKernelGGL(k_ortho, dim3(16, 6), dim3(256), 0, stream, in0, in1, in2, in3, ws);
    hipLaunchKernelGGL(k_final, dim3(1), dim3(64), 0, stream, ws, out);
}

// Round 2
// 158.695 us; speedup vs baseline: 4.0758x; 4.0758x over previous
//
#include <hip/hip_runtime.h>
#include <math.h>

// CMCV3Loss: B=512, S=8, D=128, H=64. Inputs: 4 x (4096x128 fp32), seq_len.
// Strategy: bf16-MFMA grams. loss_row = lse_{m!=n}(sim) - sim[n,pos]; fixed
// max-shift INV_T (sim <= 1/T always since vectors are normalized).
//
// ws float offsets:
#define IVSH   0        // 4*4096 inverse sh-half norms
#define IVPV   16384    // 4*4096 inverse pv-half norms
#define IVFULL 32768    // 4*4096 inverse full norms
#define RS_T   49152    // temporal rowsums [4][4096]
#define RS_C   65536    // contrastive rowsums [4 calls][8 p][1024 n]
#define SLOT   98304    // 24 accum slots, stride 32 (0..7 contrast, 8..15 temporal, 16..23 ortho)
// ws byte offsets (bf16 arrays, after float region 99328 floats = 397312 B):
#define ZF_BYTE 397312   // znfull bf16 [4][4096][128] (full-normalized)
#define ZH_BYTE 4591616  // znhalf bf16 [4][4096][128] (cols 0..63 sh-normed, 64..127 pv-normed)

#define INV_T 14.285714285714286f
#define EPS_N 1e-8f

typedef __attribute__((ext_vector_type(8))) short short8;   // 8 bf16 = 4 VGPRs
typedef __attribute__((ext_vector_type(4))) float floatx4;  // MFMA C/D frag

__device__ __forceinline__ const float* pick4(const float* a, const float* b,
                                              const float* c, const float* d, int i) {
    return i == 0 ? a : i == 1 ? b : i == 2 ? c : d;
}

__device__ __forceinline__ unsigned short f2bf(float x) {   // RNE fp32->bf16
    unsigned u = __float_as_uint(x);
    u += 0x7fff + ((u >> 16) & 1);
    return (unsigned short)(u >> 16);
}

__global__ void k_zero(float* __restrict__ ws) {
    int idx = blockIdx.x * 256 + threadIdx.x;               // grid 196*256 = 50176
    ws[RS_T + idx] = 0.0f;                                  // rowsums + slots
}

__global__ __launch_bounds__(256) void k_norm(const float* __restrict__ in0, const float* __restrict__ in1,
                                              const float* __restrict__ in2, const float* __restrict__ in3,
                                              float* __restrict__ ws) {
    int gtid = blockIdx.x * 256 + threadIdx.x;
    int wid = gtid >> 6;            // one wave per row, 16384 rows
    int lane = threadIdx.x & 63;
    int inputIdx = wid >> 12;
    int row = wid & 4095;
    const float* src = pick4(in0, in1, in2, in3, inputIdx);
    float2 v = *(const float2*)(src + (size_t)row * 128 + lane * 2);  // lanes 0..31 sh, 32..63 pv
    float s = v.x * v.x + v.y * v.y;
    #pragma unroll
    for (int off = 16; off; off >>= 1) s += __shfl_xor(s, off, 32);
    float other = __shfl_xor(s, 32, 64);
    float sh2 = (lane < 32) ? s : other;
    float pv2 = (lane < 32) ? other : s;
    if (lane == 0) {
        ws[IVSH   + inputIdx * 4096 + row] = 1.0f / fmaxf(sqrtf(sh2), EPS_N);
        ws[IVPV   + inputIdx * 4096 + row] = 1.0f / fmaxf(sqrtf(pv2), EPS_N);
        ws[IVFULL + inputIdx * 4096 + row] = 1.0f / fmaxf(sqrtf(sh2 + pv2), EPS_N);
    }
}

__global__ __launch_bounds__(256) void k_convert(const float* __restrict__ in0, const float* __restrict__ in1,
                                                 const float* __restrict__ in2, const float* __restrict__ in3,
                                                 float* __restrict__ ws) {
    int gtid = blockIdx.x * 256 + threadIdx.x;              // grid 2048: 4 elems/thread
    int base = gtid * 4;
    int inputIdx = base >> 19;                              // 4096*128 per input
    int rem = base & 524287;
    int row = rem >> 7, col = rem & 127;
    const float* src = pick4(in0, in1, in2, in3, inputIdx) + rem;
    float4 f = *(const float4*)src;
    float scF = ws[IVFULL + inputIdx * 4096 + row];
    float scH = ws[(col < 64 ? IVSH : IVPV) + inputIdx * 4096 + row];
    ushort4 of, oh;
    of.x = f2bf(f.x * scF); of.y = f2bf(f.y * scF); of.z = f2bf(f.z * scF); of.w = f2bf(f.w * scF);
    oh.x = f2bf(f.x * scH); oh.y = f2bf(f.y * scH); oh.z = f2bf(f.z * scH); oh.w = f2bf(f.w * scH);
    unsigned short* zf = (unsigned short*)((char*)ws + ZF_BYTE);
    unsigned short* zh = (unsigned short*)((char*)ws + ZH_BYTE);
    *(ushort4*)(zf + (size_t)inputIdx * 524288 + rem) = of;
    *(ushort4*)(zh + (size_t)inputIdx * 524288 + rem) = oh;
}

// ---------- temporal: 4096x4096 gram per input, 128x128 tiles ----------
// grid (1024, 4): x = rowtile*32+coltile. block 256 = 4 waves (2x2 of 64x64).
__global__ __launch_bounds__(256) void k_temporal_mfma(float* __restrict__ ws) {
    __shared__ short rowbuf[128 * 72];   // +8 shorts pad: stride 144B -> 2-way banks (free)
    __shared__ short colbuf[128 * 72];
    const int tid = threadIdx.x;
    const int inputIdx = blockIdx.y;
    const int rowbase = (blockIdx.x >> 5) * 128;
    const int colbase = (blockIdx.x & 31) * 128;
    const short* zf = (const short*)((const char*)ws + ZF_BYTE) + (size_t)inputIdx * 524288;

    floatx4 acc[4][4];
    #pragma unroll
    for (int ri = 0; ri < 4; ri++)
        #pragma unroll
        for (int ci = 0; ci < 4; ci++) acc[ri][ci] = (floatx4){0.f, 0.f, 0.f, 0.f};

    const int w = tid >> 6, lane = tid & 63, quad = (tid >> 4) & 3, l15 = tid & 15;
    const int wrow = (w >> 1) * 64, wcol = (w & 1) * 64;

    for (int kh = 0; kh < 2; kh++) {       // K=128 staged in two 64-halves (LDS fits 64KB)
        if (kh) __syncthreads();
        #pragma unroll
        for (int i = 0; i < 4; i++) {
            int e = tid + i * 256;
            int r = e >> 3, k8 = e & 7;
            *(short8*)(rowbuf + r * 72 + k8 * 8) =
                *(const short8*)(zf + (size_t)(rowbase + r) * 128 + kh * 64 + k8 * 8);
            *(short8*)(colbuf + r * 72 + k8 * 8) =
                *(const short8*)(zf + (size_t)(colbase + r) * 128 + kh * 64 + k8 * 8);
        }
        __syncthreads();
        #pragma unroll
        for (int ks = 0; ks < 2; ks++) {
            short8 a[4], b[4];
            int ko = ks * 32 + quad * 8;
            #pragma unroll
            for (int i = 0; i < 4; i++) {
                a[i] = *(const short8*)(rowbuf + (wrow + i * 16 + l15) * 72 + ko);
                b[i] = *(const short8*)(colbuf + (wcol + i * 16 + l15) * 72 + ko);
            }
            #pragma unroll
            for (int ri = 0; ri < 4; ri++)
                #pragma unroll
                for (int ci = 0; ci < 4; ci++)
                    acc[ri][ci] = __builtin_amdgcn_mfma_f32_16x16x32_bf16(a[ri], b[ci], acc[ri][ci], 0, 0, 0);
        }
    }

    // epilogue: C frag layout col=l15, row=quad*4+reg
    float* rowsum = ws + RS_T + inputIdx * 4096;
    float ppart = 0.f;
    #pragma unroll
    for (int ri = 0; ri < 4; ri++) {
        #pragma unroll
        for (int reg = 0; reg < 4; reg++) {
            int r = rowbase + wrow + ri * 16 + quad * 4 + reg;
            int poscol = (r & ~7) | ((r & 7) ? 0 : 1);
            float rp = 0.f;
            #pragma unroll
            for (int ci = 0; ci < 4; ci++) {
                int c0 = colbase + wcol + ci * 16 + l15;
                float v = acc[ri][ci][reg] * INV_T;
                float ex = __expf(v - INV_T);
                rp += (c0 != r) ? ex : 0.f;
                ppart += (c0 == poscol) ? v : 0.f;
            }
            rp += __shfl_xor(rp, 1); rp += __shfl_xor(rp, 2);
            rp += __shfl_xor(rp, 4); rp += __shfl_xor(rp, 8);
            if (l15 == 0) atomicAdd(rowsum + r, rp);
        }
    }
    #pragma unroll
    for (int m = 1; m < 64; m <<= 1) ppart += __shfl_xor(ppart, m);
    if (lane == 0 && ppart != 0.f)
        atomicAdd(ws + SLOT + 32 * (8 + (blockIdx.x & 7)), -ppart);
}

// ---------- contrastive: per (call,p), 1024x1024 gram over 64-d halves ----------
// grid (64, 8, 4): x = rowtile*8+coltile. n -> src row (n&511)*8+p, col range off..off+63.
__global__ __launch_bounds__(256) void k_contrastive_mfma(float* __restrict__ ws) {
    __shared__ short rowbuf[128 * 72];
    __shared__ short colbuf[128 * 72];
    const int tid = threadIdx.x;
    const int call = blockIdx.z, p = blockIdx.y;
    const int rowbase = (blockIdx.x >> 3) * 128;
    const int colbase = (blockIdx.x & 7) * 128;

    int aIdx, bIdx, off;
    if (call == 0)      { aIdx = 0; bIdx = 2; off = 0; }   // sh(mod1_v1) vs sh(mod2_v1)
    else if (call == 1) { aIdx = 1; bIdx = 3; off = 0; }
    else if (call == 2) { aIdx = 0; bIdx = 1; off = 64; }  // pv(v1) vs pv(v2)
    else                { aIdx = 2; bIdx = 3; off = 64; }
    const short* zh = (const short*)((const char*)ws + ZH_BYTE);
    const short* srcR = zh + (size_t)(rowbase < 512 ? aIdx : bIdx) * 524288;
    const short* srcC = zh + (size_t)(colbase < 512 ? aIdx : bIdx) * 524288;
    const int rb = rowbase & 511, cb = colbase & 511;

    floatx4 acc[4][4];
    #pragma unroll
    for (int ri = 0; ri < 4; ri++)
        #pragma unroll
        for (int ci = 0; ci < 4; ci++) acc[ri][ci] = (floatx4){0.f, 0.f, 0.f, 0.f};

    const int w = tid >> 6, lane = tid & 63, quad = (tid >> 4) & 3, l15 = tid & 15;
    const int wrow = (w >> 1) * 64, wcol = (w & 1) * 64;

    #pragma unroll
    for (int i = 0; i < 4; i++) {          // stage 128 n's x 64 bf16, each
        int e = tid + i * 256;
        int r = e >> 3, k8 = e & 7;
        *(short8*)(rowbuf + r * 72 + k8 * 8) =
            *(const short8*)(srcR + (size_t)((rb + r) * 8 + p) * 128 + off + k8 * 8);
        *(short8*)(colbuf + r * 72 + k8 * 8) =
            *(const short8*)(srcC + (size_t)((cb + r) * 8 + p) * 128 + off + k8 * 8);
    }
    __syncthreads();
    #pragma unroll
    for (int ks = 0; ks < 2; ks++) {       // K=64
        short8 a[4], b[4];
        int ko = ks * 32 + quad * 8;
        #pragma unroll
        for (int i = 0; i < 4; i++) {
            a[i] = *(const short8*)(rowbuf + (wrow + i * 16 + l15) * 72 + ko);
            b[i] = *(const short8*)(colbuf + (wcol + i * 16 + l15) * 72 + ko);
        }
        #pragma unroll
        for (int ri = 0; ri < 4; ri++)
            #pragma unroll
            for (int ci = 0; ci < 4; ci++)
                acc[ri][ci] = __builtin_amdgcn_mfma_f32_16x16x32_bf16(a[ri], b[ci], acc[ri][ci], 0, 0, 0);
    }

    float* rowsum = ws + RS_C + (call * 8 + p) * 1024;
    float ppart = 0.f;
    #pragma unroll
    for (int ri = 0; ri < 4; ri++) {
        #pragma unroll
        for (int reg = 0; reg < 4; reg++) {
            int n = rowbase + wrow + ri * 16 + quad * 4 + reg;
            int posc = n ^ 512;
            float rp = 0.f;
            #pragma unroll
            for (int ci = 0; ci < 4; ci++) {
                int c0 = colbase + wcol + ci * 16 + l15;
                float v = acc[ri][ci][reg] * INV_T;
                float ex = __expf(v - INV_T);
                rp += (c0 != n) ? ex : 0.f;
                ppart += (c0 == posc) ? v : 0.f;
            }
            rp += __shfl_xor(rp, 1); rp += __shfl_xor(rp, 2);
            rp += __shfl_xor(rp, 4); rp += __shfl_xor(rp, 8);
            if (l15 == 0) atomicAdd(rowsum + n, rp);
        }
    }
    #pragma unroll
    for (int m = 1; m < 64; m <<= 1) ppart += __shfl_xor(ppart, m);
    if (lane == 0 && ppart != 0.f)
        atomicAdd(ws + SLOT + 32 * (blockIdx.x & 7), -ppart);
}

// ---------- ortho: mean(relu(cos)), 6 terms x 4096 rows ----------
__global__ __launch_bounds__(256) void k_ortho(const float* __restrict__ in0, const float* __restrict__ in1,
                                               const float* __restrict__ in2, const float* __restrict__ in3,
                                               float* __restrict__ ws) {
    const int term = blockIdx.y;
    const int row = blockIdx.x * 256 + threadIdx.x;
    int aIdx, aOff, bIdx, bOff;
    switch (term) {
        case 0:  aIdx = 0; aOff = 0;  bIdx = 0; bOff = 64; break;
        case 1:  aIdx = 2; aOff = 0;  bIdx = 2; bOff = 64; break;
        case 2:  aIdx = 1; aOff = 0;  bIdx = 1; bOff = 64; break;
        case 3:  aIdx = 3; aOff = 0;  bIdx = 3; bOff = 64; break;
        case 4:  aIdx = 0; aOff = 64; bIdx = 2; bOff = 64; break;
        default: aIdx = 1; aOff = 64; bIdx = 3; bOff = 64; break;
    }
    const float* A  = pick4(in0, in1, in2, in3, aIdx) + (size_t)row * 128 + aOff;
    const float* Bv = pick4(in0, in1, in2, in3, bIdx) + (size_t)row * 128 + bOff;
    float ia = ws[(aOff ? IVPV : IVSH) + aIdx * 4096 + row];
    float ib = ws[(bOff ? IVPV : IVSH) + bIdx * 4096 + row];
    float d = 0.0f;
    #pragma unroll
    for (int k = 0; k < 16; k++) {
        float4 x = *(const float4*)(A + k * 4);
        float4 y = *(const float4*)(Bv + k * 4);
        d = fmaf(x.x, y.x, fmaf(x.y, y.y, fmaf(x.z, y.z, fmaf(x.w, y.w, d))));
    }
    float val = fmaxf(d * ia * ib, 0.0f);
    #pragma unroll
    for (int off = 32; off; off >>= 1) val += __shfl_xor(val, off);
    if ((threadIdx.x & 63) == 0)
        atomicAdd(ws + SLOT + 32 * (16 + ((blockIdx.x + blockIdx.y) & 7)), val);
}

__global__ __launch_bounds__(256) void k_logsum(float* __restrict__ ws) {
    int idx = blockIdx.x * 256 + threadIdx.x;   // grid 192: 64 blocks temporal, 128 contrastive
    float v;
    int slot;
    if (idx < 16384) { v = __logf(ws[RS_T + idx]); slot = 8 + (blockIdx.x & 7); }
    else             { v = __logf(ws[RS_C + idx - 16384]); slot = blockIdx.x & 7; }
    #pragma unroll
    for (int m = 1; m < 64; m <<= 1) v += __shfl_xor(v, m);
    if ((threadIdx.x & 63) == 0) atomicAdd(ws + SLOT + 32 * slot, v);
}

__global__ void k_final(const float* __restrict__ ws, float* __restrict__ out) {
    if (threadIdx.x == 0) {
        float cs = 0.f, ts = 0.f, os = 0.f;
        for (int i = 0; i < 8; i++) {
            cs += ws[SLOT + 32 * i];
            ts += ws[SLOT + 32 * (8 + i)];
            os += ws[SLOT + 32 * (16 + i)];
        }
        out[0] = (cs + 32768.0f * INV_T) / 8192.0f
               + (ts + 16384.0f * INV_T) / 4096.0f
               + os / 4096.0f;
    }
}

extern "C" void kernel_launch(void* const* d_in, const int* in_sizes, int n_in,
                              void* d_out, int out_size, void* d_ws, size_t ws_size,
                              hipStream_t stream) {
    (void)in_sizes; (void)n_in; (void)out_size; (void)ws_size;
    const float* in0 = (const float*)d_in[0];
    const float* in1 = (const float*)d_in[1];
    const float* in2 = (const float*)d_in[2];
    const float* in3 = (const float*)d_in[3];
    float* ws = (float*)d_ws;
    float* out = (float*)d_out;

    hipLaunchKernelGGL(k_zero, dim3(196), dim3(256), 0, stream, ws);
    hipLaunchKernelGGL(k_norm, dim3(4096), dim3(256), 0, stream, in0, in1, in2, in3, ws);
    hipLaunchKernelGGL(k_convert, dim3(2048), dim3(256), 0, stream, in0, in1, in2, in3, ws);
    hipLaunchKernelGGL(k_contrastive_mfma, dim3(64, 8, 4), dim3(256), 0, stream, ws);
    hipLaunchKernelGGL(k_temporal_mfma, dim3(1024, 4), dim3(256), 0, stream, ws);
    hipLaunchKernelGGL(k_ortho, dim3(16, 6), dim3(256), 0, stream, in0, in1, in2, in3, ws);
    hipLaunchKernelGGL(k_logsum, dim3(192), dim3(256), 0, stream, ws);
    hipLaunchKernelGGL(k_final, dim3(1), dim3(64), 0, stream, ws, out);
}

// Round 3
// 143.346 us; speedup vs baseline: 4.5122x; 1.1071x over previous
//
#include <hip/hip_runtime.h>
#include <math.h>

// CMCV3Loss: B=512, S=8, D=128, H=64. Inputs: 4 x (4096x128 fp32), seq_len.
// bf16-MFMA symmetric grams; loss_row = lse_{m!=n} - pos. Fixed max-shift:
// ex = exp((s-1)*INV_T) = exp2(fma(s, C1EXP, -C1EXP)) since s<=1 for normalized vecs.
//
// ws float offsets:
#define IVSH   0        // 4*4096 inverse sh-half norms
#define IVPV   16384
#define IVFULL 32768
#define RS_T   49152    // temporal rowsums [4][4096]
#define RS_C   65536    // contrastive rowsums [4 calls][8 p][1024]
#define SLOT   98304    // 32 slots stride 32: 0..7 c-log, 8..15 t-log, 16..23 ortho, 24 posC, 25 posT
// ws byte offsets (bf16 arrays):
#define ZF_BYTE 397312   // znfull bf16 [4][4096][128]
#define ZH_BYTE 4591616  // znhalf bf16 [4][4096][128] (cols 0..63 sh-normed, 64..127 pv-normed)

#define INV_T 14.285714285714286f
#define C1EXP 20.609929155556627f   // INV_T * log2(e)
#define EPS_N 1e-8f

typedef __attribute__((ext_vector_type(8))) short short8;
typedef __attribute__((ext_vector_type(4))) float floatx4;

__device__ __forceinline__ const float* pick4(const float* a, const float* b,
                                              const float* c, const float* d, int i) {
    return i == 0 ? a : i == 1 ? b : i == 2 ? c : d;
}

__device__ __forceinline__ unsigned short f2bf(float x) {
    unsigned u = __float_as_uint(x);
    u += 0x7fff + ((u >> 16) & 1);
    return (unsigned short)(u >> 16);
}

// norms + zero the rowsum/slot region (49152..99328)
__global__ __launch_bounds__(256) void k_norm(const float* __restrict__ in0, const float* __restrict__ in1,
                                              const float* __restrict__ in2, const float* __restrict__ in3,
                                              float* __restrict__ ws) {
    int gid = blockIdx.x * 256 + threadIdx.x;
    if (gid < 50176) ws[RS_T + gid] = 0.0f;
    int wid = gid >> 6;
    int lane = threadIdx.x & 63;
    int inputIdx = wid >> 12;
    int row = wid & 4095;
    const float* src = pick4(in0, in1, in2, in3, inputIdx);
    float2 v = *(const float2*)(src + (size_t)row * 128 + lane * 2);
    float s = v.x * v.x + v.y * v.y;
    #pragma unroll
    for (int off = 16; off; off >>= 1) s += __shfl_xor(s, off, 32);
    float other = __shfl_xor(s, 32, 64);
    float sh2 = (lane < 32) ? s : other;
    float pv2 = (lane < 32) ? other : s;
    if (lane == 0) {
        ws[IVSH   + inputIdx * 4096 + row] = 1.0f / fmaxf(sqrtf(sh2), EPS_N);
        ws[IVPV   + inputIdx * 4096 + row] = 1.0f / fmaxf(sqrtf(pv2), EPS_N);
        ws[IVFULL + inputIdx * 4096 + row] = 1.0f / fmaxf(sqrtf(sh2 + pv2), EPS_N);
    }
}

__global__ __launch_bounds__(256) void k_convert(const float* __restrict__ in0, const float* __restrict__ in1,
                                                 const float* __restrict__ in2, const float* __restrict__ in3,
                                                 float* __restrict__ ws) {
    int gtid = blockIdx.x * 256 + threadIdx.x;
    int base = gtid * 4;
    int inputIdx = base >> 19;
    int rem = base & 524287;
    int row = rem >> 7, col = rem & 127;
    const float* src = pick4(in0, in1, in2, in3, inputIdx) + rem;
    float4 f = *(const float4*)src;
    float scF = ws[IVFULL + inputIdx * 4096 + row];
    float scH = ws[(col < 64 ? IVSH : IVPV) + inputIdx * 4096 + row];
    ushort4 of, oh;
    of.x = f2bf(f.x * scF); of.y = f2bf(f.y * scF); of.z = f2bf(f.z * scF); of.w = f2bf(f.w * scF);
    oh.x = f2bf(f.x * scH); oh.y = f2bf(f.y * scH); oh.z = f2bf(f.z * scH); oh.w = f2bf(f.w * scH);
    unsigned short* zf = (unsigned short*)((char*)ws + ZF_BYTE);
    unsigned short* zh = (unsigned short*)((char*)ws + ZH_BYTE);
    *(ushort4*)(zf + (size_t)inputIdx * 524288 + rem) = of;
    *(ushort4*)(zh + (size_t)inputIdx * 524288 + rem) = oh;
}

// ortho (6 terms) + contrastive pos + temporal pos, fp32, per 8-row sequence
__global__ __launch_bounds__(256) void k_dots(const float* __restrict__ in0, const float* __restrict__ in1,
                                              const float* __restrict__ in2, const float* __restrict__ in3,
                                              float* __restrict__ ws) {
    __shared__ float buf[4][8][128];
    __shared__ float red[3];
    const int s = blockIdx.x;       // 512 sequences
    const int tid = threadIdx.x;
    if (tid < 3) red[tid] = 0.0f;
    #pragma unroll
    for (int i = 0; i < 4; i++) {
        int e4 = tid + i * 256;
        int inp = e4 >> 8, row = (e4 >> 5) & 7, c4 = e4 & 31;
        float4 f = *(const float4*)(pick4(in0, in1, in2, in3, inp) + (size_t)(s * 8 + row) * 128 + c4 * 4);
        *(float4*)(&buf[inp][row][c4 * 4]) = f;
    }
    __syncthreads();

    float val = 0.0f;
    int cat = -1;
    if (tid < 48) {                 // ortho: relu(cos) per row
        const int oa[6]  = {0, 2, 1, 3, 0, 1};
        const int oaf[6] = {0, 0, 0, 0, 64, 64};
        const int ob[6]  = {0, 2, 1, 3, 2, 3};
        int term = tid >> 3, row = tid & 7;
        const float* A = &buf[oa[term]][row][oaf[term]];
        const float* B = &buf[ob[term]][row][64];
        float d = 0.0f;
        #pragma unroll
        for (int k = 0; k < 16; k++) {
            float4 x = *(const float4*)(A + k * 4);
            float4 y = *(const float4*)(B + k * 4);
            d = fmaf(x.x, y.x, fmaf(x.y, y.y, fmaf(x.z, y.z, fmaf(x.w, y.w, d))));
        }
        float ia = ws[(oaf[term] ? IVPV : IVSH) + oa[term] * 4096 + s * 8 + row];
        float ib = ws[IVPV + ob[term] * 4096 + s * 8 + row];
        val = fmaxf(d * ia * ib, 0.0f);
        cat = 2;
    } else if (tid < 80) {          // contrastive pos: dot_half(A[r], B[r])
        const int ca[4] = {0, 1, 0, 2}, cb[4] = {2, 3, 1, 3}, coff[4] = {0, 0, 64, 64};
        int call = (tid - 48) >> 3, row = (tid - 48) & 7;
        const float* A = &buf[ca[call]][row][coff[call]];
        const float* B = &buf[cb[call]][row][coff[call]];
        float d = 0.0f;
        #pragma unroll
        for (int k = 0; k < 16; k++) {
            float4 x = *(const float4*)(A + k * 4);
            float4 y = *(const float4*)(B + k * 4);
            d = fmaf(x.x, y.x, fmaf(x.y, y.y, fmaf(x.z, y.z, fmaf(x.w, y.w, d))));
        }
        int ivb = coff[call] ? IVPV : IVSH;
        val = d * ws[ivb + ca[call] * 4096 + s * 8 + row] * ws[ivb + cb[call] * 4096 + s * 8 + row];
        cat = 0;
    } else if (tid < 136) {         // temporal pos: d(0,1)*2 + sum_{j=2..7} d(j,0), as 64-d halves
        int u = tid - 80;
        int inp = u / 14, v = u % 14, pp = v >> 1, half = v & 1;
        int ra = (pp == 0) ? 1 : (pp + 1);
        const float* A = &buf[inp][ra][half * 64];
        const float* B = &buf[inp][0][half * 64];
        float d = 0.0f;
        #pragma unroll
        for (int k = 0; k < 16; k++) {
            float4 x = *(const float4*)(A + k * 4);
            float4 y = *(const float4*)(B + k * 4);
            d = fmaf(x.x, y.x, fmaf(x.y, y.y, fmaf(x.z, y.z, fmaf(x.w, y.w, d))));
        }
        float wgt = (pp == 0) ? 2.0f : 1.0f;
        val = d * wgt * ws[IVFULL + inp * 4096 + s * 8 + ra] * ws[IVFULL + inp * 4096 + s * 8];
        cat = 1;
    }
    if (cat >= 0) atomicAdd(&red[cat], val);
    __syncthreads();
    if (tid == 0) atomicAdd(ws + SLOT + 32 * 24, red[0]);
    if (tid == 1) atomicAdd(ws + SLOT + 32 * 25, red[1]);
    if (tid == 2) atomicAdd(ws + SLOT + 32 * (16 + (s & 7)), red[2]);
}

// unified symmetric gram: blocks [0,2176) temporal (4 inputs x 544), [2176,3456) contrastive (32 x 40)
__global__ __launch_bounds__(256) void k_gram(float* __restrict__ ws) {
    __shared__ short rowbuf[128 * 72];
    __shared__ short colbuf[128 * 72];
    const int tid = threadIdx.x;
    const int b = blockIdx.x;

    const short* baseR;
    const short* baseC;
    int rstride, nk;
    float* rsR;
    float* rsC;
    bool diag;
    int slot;

    if (b < 2176) {
        int input = b / 544, t = b % 544;
        int j = t >> 5, i = t & 31;
        if (j == 16 && i >= 16) return;          // folded duplicate
        int rt = i, ct = (i + j) & 31;
        diag = (j == 0);
        const short* zf = (const short*)((const char*)ws + ZF_BYTE) + (size_t)input * 524288;
        baseR = zf + rt * 16384;
        baseC = zf + ct * 16384;
        rstride = 128; nk = 2;
        rsR = ws + RS_T + input * 4096 + rt * 128;
        rsC = ws + RS_T + input * 4096 + ct * 128;
        slot = 8 + (b & 7);
        (void)slot;
    } else {
        int c = b - 2176;
        int callp = c / 40, t = c % 40;
        int j = t >> 3, i = t & 7;
        if (j == 4 && i >= 4) return;
        int call = callp >> 3, p = callp & 7;
        int rt = i, ct = (i + j) & 7;
        diag = (j == 0);
        const int ca[4] = {0, 1, 0, 2}, cb[4] = {2, 3, 1, 3}, coff[4] = {0, 0, 64, 64};
        const short* zh = (const short*)((const char*)ws + ZH_BYTE);
        int rbase = rt * 128, cbase = ct * 128;
        baseR = zh + (size_t)(rbase < 512 ? ca[call] : cb[call]) * 524288
                   + (size_t)((rbase & 511) * 8 + p) * 128 + coff[call];
        baseC = zh + (size_t)(cbase < 512 ? ca[call] : cb[call]) * 524288
                   + (size_t)((cbase & 511) * 8 + p) * 128 + coff[call];
        rstride = 1024; nk = 1;
        rsR = ws + RS_C + (call * 8 + p) * 1024 + rbase;
        rsC = ws + RS_C + (call * 8 + p) * 1024 + cbase;
    }

    floatx4 acc[4][4];
    #pragma unroll
    for (int ri = 0; ri < 4; ri++)
        #pragma unroll
        for (int ci = 0; ci < 4; ci++) acc[ri][ci] = (floatx4){0.f, 0.f, 0.f, 0.f};

    const int w = tid >> 6, lane = tid & 63, quad = (tid >> 4) & 3, l15 = tid & 15;
    const int wrow = (w >> 1) * 64, wcol = (w & 1) * 64;
    const short* bbuf = diag ? rowbuf : colbuf;

    for (int st = 0; st < nk; st++) {
        if (st) __syncthreads();
        const int kbase = st * 64;
        #pragma unroll
        for (int i = 0; i < 4; i++) {
            int e = tid + i * 256, r = e >> 3, k8 = e & 7;
            *(short8*)(rowbuf + r * 72 + k8 * 8) =
                *(const short8*)(baseR + (size_t)r * rstride + kbase + k8 * 8);
            if (!diag)
                *(short8*)(colbuf + r * 72 + k8 * 8) =
                    *(const short8*)(baseC + (size_t)r * rstride + kbase + k8 * 8);
        }
        __syncthreads();
        #pragma unroll
        for (int ks = 0; ks < 2; ks++) {
            short8 a[4], bb[4];
            int ko = ks * 32 + quad * 8;
            #pragma unroll
            for (int i = 0; i < 4; i++) {
                a[i]  = *(const short8*)(rowbuf + (wrow + i * 16 + l15) * 72 + ko);
                bb[i] = *(const short8*)(bbuf   + (wcol + i * 16 + l15) * 72 + ko);
            }
            #pragma unroll
            for (int ri = 0; ri < 4; ri++)
                #pragma unroll
                for (int ci = 0; ci < 4; ci++)
                    acc[ri][ci] = __builtin_amdgcn_mfma_f32_16x16x32_bf16(a[ri], bb[ci], acc[ri][ci], 0, 0, 0);
        }
    }

    // epilogue: C layout col=l15, row=quad*4+reg
    if (diag) {
        #pragma unroll
        for (int ri = 0; ri < 4; ri++) {
            #pragma unroll
            for (int reg = 0; reg < 4; reg++) {
                int rloc = wrow + ri * 16 + quad * 4 + reg;
                float rp = 0.f;
                #pragma unroll
                for (int ci = 0; ci < 4; ci++) {
                    int cloc = wcol + ci * 16 + l15;
                    float ex = __builtin_amdgcn_exp2f(fmaf(acc[ri][ci][reg], C1EXP, -C1EXP));
                    rp += (cloc != rloc) ? ex : 0.f;   // exact diag exclusion
                }
                rp += __shfl_xor(rp, 1); rp += __shfl_xor(rp, 2);
                rp += __shfl_xor(rp, 4); rp += __shfl_xor(rp, 8);
                if (l15 == 0) atomicAdd(rsR + rloc, rp);
            }
        }
    } else {
        float colp[4] = {0.f, 0.f, 0.f, 0.f};
        #pragma unroll
        for (int ri = 0; ri < 4; ri++) {
            #pragma unroll
            for (int reg = 0; reg < 4; reg++) {
                int rloc = wrow + ri * 16 + quad * 4 + reg;
                float rp = 0.f;
                #pragma unroll
                for (int ci = 0; ci < 4; ci++) {
                    float ex = __builtin_amdgcn_exp2f(fmaf(acc[ri][ci][reg], C1EXP, -C1EXP));
                    rp += ex;
                    colp[ci] += ex;
                }
                rp += __shfl_xor(rp, 1); rp += __shfl_xor(rp, 2);
                rp += __shfl_xor(rp, 4); rp += __shfl_xor(rp, 8);
                if (l15 == 0) atomicAdd(rsR + rloc, rp);
            }
        }
        #pragma unroll
        for (int ci = 0; ci < 4; ci++) {           // transpose contribution
            colp[ci] += __shfl_xor(colp[ci], 16);
            colp[ci] += __shfl_xor(colp[ci], 32);
            if (lane < 16) atomicAdd(rsC + wcol + ci * 16 + l15, colp[ci]);
        }
    }
}

__global__ __launch_bounds__(256) void k_logsum(float* __restrict__ ws) {
    int idx = blockIdx.x * 256 + threadIdx.x;   // 192 blocks: 16384 temporal + 32768 contrastive
    float v;
    int slot;
    if (idx < 16384) { v = __logf(ws[RS_T + idx]); slot = 8 + (blockIdx.x & 7); }
    else             { v = __logf(ws[RS_C + idx - 16384]); slot = blockIdx.x & 7; }
    #pragma unroll
    for (int m = 1; m < 64; m <<= 1) v += __shfl_xor(v, m);
    if ((threadIdx.x & 63) == 0) atomicAdd(ws + SLOT + 32 * slot, v);
}

__global__ void k_final(const float* __restrict__ ws, float* __restrict__ out) {
    if (threadIdx.x == 0) {
        float cs = 0.f, ts = 0.f, os = 0.f;
        for (int i = 0; i < 8; i++) {
            cs += ws[SLOT + 32 * i];
            ts += ws[SLOT + 32 * (8 + i)];
            os += ws[SLOT + 32 * (16 + i)];
        }
        float posC = ws[SLOT + 32 * 24], posT = ws[SLOT + 32 * 25];
        out[0] = (cs + 32768.0f * INV_T - 2.0f * INV_T * posC) * (1.0f / 8192.0f)
               + (ts + 16384.0f * INV_T - INV_T * posT) * (1.0f / 4096.0f)
               + os * (1.0f / 4096.0f);
    }
}

extern "C" void kernel_launch(void* const* d_in, const int* in_sizes, int n_in,
                              void* d_out, int out_size, void* d_ws, size_t ws_size,
                              hipStream_t stream) {
    (void)in_sizes; (void)n_in; (void)out_size; (void)ws_size;
    const float* in0 = (const float*)d_in[0];
    const float* in1 = (const float*)d_in[1];
    const float* in2 = (const float*)d_in[2];
    const float* in3 = (const float*)d_in[3];
    float* ws = (float*)d_ws;
    float* out = (float*)d_out;

    hipLaunchKernelGGL(k_norm, dim3(4096), dim3(256), 0, stream, in0, in1, in2, in3, ws);
    hipLaunchKernelGGL(k_convert, dim3(2048), dim3(256), 0, stream, in0, in1, in2, in3, ws);
    hipLaunchKernelGGL(k_dots, dim3(512), dim3(256), 0, stream, in0, in1, in2, in3, ws);
    hipLaunchKernelGGL(k_gram, dim3(3456), dim3(256), 0, stream, ws);
    hipLaunchKernelGGL(k_logsum, dim3(192), dim3(256), 0, stream, ws);
    hipLaunchKernelGGL(k_final, dim3(1), dim3(64), 0, stream, ws, out);
}